// Round 8
// baseline (2900.118 us; speedup 1.0000x reference)
//
#include <hip/hip_runtime.h>

#define TSTEPS 784
#define BATCH  256
#define HDIM   512
#define NCLS   10
#define NGRP   16   // independent batch groups (16 rows each)
#define WGPG   8    // workgroups per group (8 col-blocks of 64 cols)

typedef __bf16 bf16x8 __attribute__((ext_vector_type(8)));
typedef float  f32x4  __attribute__((ext_vector_type(4)));
typedef unsigned uint4v __attribute__((ext_vector_type(4)));
typedef unsigned long long u64;

static __device__ __forceinline__ unsigned short f2bf(float f) {
  unsigned u = __builtin_bit_cast(unsigned, f);
  u += 0x7fffu + ((u >> 16) & 1u);
  return (unsigned short)(u >> 16);
}
static __device__ __forceinline__ float bf2f(unsigned s) {
  unsigned u = s << 16;
  return __builtin_bit_cast(float, u);
}
static __device__ __forceinline__ u64 ald(const u64* p) {
  return __hip_atomic_load(p, __ATOMIC_RELAXED, __HIP_MEMORY_SCOPE_AGENT);
}
static __device__ __forceinline__ void ast(u64* p, u64 v) {
  __hip_atomic_store(p, v, __ATOMIC_RELAXED, __HIP_MEMORY_SCOPE_AGENT);
}

// ---------------- xp[t][b] = inputs[b][perm[t]] ----------------
__global__ __launch_bounds__(256) void gather_xp(const float* __restrict__ in,
                                                 const int* __restrict__ perm,
                                                 float* __restrict__ xp) {
  int t = blockIdx.x;
  int b = threadIdx.x;
  int p = perm[t];
  p = (p < 0) ? 0 : (p >= TSTEPS ? TSTEPS - 1 : p);
  xp[t * BATCH + b] = in[b * TSTEPS + p];
}

// ---------------- X = (triu(W,1) - triu(W,1)^T) / 32 ----------------
__global__ __launch_bounds__(256) void build_X(const float* __restrict__ W,
                                               float* __restrict__ X) {
  int idx = blockIdx.x * 256 + threadIdx.x;
  int i = idx >> 9, j = idx & 511;
  float v = 0.f;
  if (j > i) v = W[i * HDIM + j];
  else if (i > j) v = -W[j * HDIM + i];
  X[idx] = v * 0.03125f;
}

// ---------------- P = coef*X + I ----------------
__global__ __launch_bounds__(256) void axpyI(float* __restrict__ P,
                                             const float* __restrict__ X, float coef) {
  int idx = blockIdx.x * 256 + threadIdx.x;
  int i = idx >> 9, j = idx & 511;
  P[idx] = coef * X[idx] + ((i == j) ? 1.f : 0.f);
}

// ---------------- C = alpha*A*B (+I), 512^3 fp32, 64x64 tile ----------------
__global__ __launch_bounds__(256) void gemm512(float* __restrict__ C,
                                               const float* __restrict__ A,
                                               const float* __restrict__ B,
                                               float alpha, int addI) {
  __shared__ float As[16][68];
  __shared__ float Bs[16][68];
  const int tx = threadIdx.x, ty = threadIdx.y;
  const int tid = ty * 16 + tx;
  const int ib = blockIdx.y, jb = blockIdx.x;
  const int ra = tid >> 2, ca = (tid & 3) << 2;
  const int rb = tid >> 4, cb = (tid & 15) << 2;
  float acc[4][4] = {};
  for (int kt = 0; kt < HDIM / 16; ++kt) {
    f32x4 av = *(const f32x4*)(A + (ib * 64 + ra) * HDIM + kt * 16 + ca);
    f32x4 bv = *(const f32x4*)(B + (kt * 16 + rb) * HDIM + jb * 64 + cb);
    __syncthreads();
    As[ca + 0][ra] = av[0];
    As[ca + 1][ra] = av[1];
    As[ca + 2][ra] = av[2];
    As[ca + 3][ra] = av[3];
    *(f32x4*)&Bs[rb][cb] = bv;
    __syncthreads();
#pragma unroll
    for (int kk = 0; kk < 16; ++kk) {
      f32x4 a4 = *(const f32x4*)&As[kk][ty << 2];
      f32x4 b4 = *(const f32x4*)&Bs[kk][tx << 2];
#pragma unroll
      for (int u = 0; u < 4; ++u)
#pragma unroll
        for (int v = 0; v < 4; ++v) acc[u][v] = fmaf(a4[u], b4[v], acc[u][v]);
    }
  }
#pragma unroll
  for (int u = 0; u < 4; ++u)
#pragma unroll
    for (int v = 0; v < 4; ++v) {
      int r = ib * 64 + (ty << 2) + u, c = jb * 64 + (tx << 2) + v;
      float val = alpha * acc[u][v];
      if (addI && r == c) val += 1.f;
      C[r * HDIM + c] = val;
    }
}

// ---------------- persistent RNN scan, tagged-dataflow exchange ----------------
// 128 WGs x 256 thr (4 waves). gb = wg&15 (batch group), cg = wg>>4 in 0..7.
// h element = 8B (packed bf16 hi/lo | step tag<<32), ONE atomic u64 store =>
// data is self-announcing: consumers poll (tag == t) on the data itself.
// No flags, no fences, no store drain. 2-buffer ping-pong is race-free:
// writing h_{t+2} requires having verified ALL of h_{t+1}, which implies every
// WG finished polling h_t (stale tags just fail the compare). All poll loops
// valve-bounded: worst failure = wrong answer, never a hang.
__global__ __launch_bounds__(256, 1) void rnn_main(
    const float* __restrict__ xp, const float* __restrict__ Borth,
    const float* __restrict__ W_in, const float* __restrict__ b_mod,
    const float* __restrict__ W_lin, const float* __restrict__ b_lin,
    u64* __restrict__ h0, u64* __restrict__ h1, float* __restrict__ out) {
  __shared__ unsigned tileA[16 * HDIM];  // 32 KB, swizzled [row16][k512]

  const int wg = blockIdx.x;
  const int gb = wg & 15;   // batch group: rows [gb*16, gb*16+16)
  const int cg = wg >> 4;   // col block:   cols [cg*64, cg*64+64)
  const int tid = threadIdx.x;
  const int wave = tid >> 6;
  const int lane = tid & 63;
  const int quad = lane >> 4;
  const int l16 = lane & 15;
  const int colg = (cg << 6) + (wave << 4) + l16;  // this lane's output column

  // B fragments (compiler holds these in AGPRs; MFMA reads B from AGPR)
  bf16x8 Bhi[16], Blo[16];
#pragma unroll
  for (int ki = 0; ki < 16; ++ki) {
#pragma unroll
    for (int j = 0; j < 8; ++j) {
      int k = (ki << 5) + (quad << 3) + j;
      float v = Borth[k * HDIM + colg];
      unsigned short hb = f2bf(v);
      unsigned short lb = f2bf(v - bf2f(hb));
      Bhi[ki][j] = __builtin_bit_cast(__bf16, hb);
      Blo[ki][j] = __builtin_bit_cast(__bf16, lb);
    }
  }
  const float win = W_in[colg];
  const float bm = b_mod[colg];

  u64* const g0 = h0 + (gb << 13);  // 8192 elements per group (16 rows x 512)
  u64* const g1 = h1 + (gb << 13);
  const int e0 = tid << 1;  // this thread stages cols (2tid, 2tid+1) of each row

  for (int t = 0; t < TSTEPS; ++t) {
    const u64* __restrict__ cur = (t & 1) ? g1 : g0;  // holds h_t, tag t
    u64* __restrict__ nxt = (t & 1) ? g0 : g1;        // gets h_{t+1}, tag t+1
    const unsigned tg = (unsigned)t;

    // ---- tagged poll-stage: 32 u64 loads in flight; retry only misses ----
    u64 qa[16], qb[16];
#pragma unroll
    for (int i = 0; i < 16; ++i) {
      qa[i] = ald(cur + (i << 9) + e0);
      qb[i] = ald(cur + (i << 9) + e0 + 1);
    }
    int spin = 0;
    for (;;) {
      bool ok = true;
#pragma unroll
      for (int i = 0; i < 16; ++i)
        ok = ok && ((unsigned)(qa[i] >> 32) == tg) && ((unsigned)(qb[i] >> 32) == tg);
      if (__ballot(ok) == ~0ull) break;
      if (++spin > (1 << 20)) break;  // anti-hang valve
      __builtin_amdgcn_s_sleep(1);
#pragma unroll
      for (int i = 0; i < 16; ++i) {
        if ((unsigned)(qa[i] >> 32) != tg) qa[i] = ald(cur + (i << 9) + e0);
        if ((unsigned)(qb[i] >> 32) != tg) qb[i] = ald(cur + (i << 9) + e0 + 1);
      }
    }
    // swizzled LDS write (R6-proven): phys = (row<<9) | (dcol ^ ((row&7)<<2))
#pragma unroll
    for (int i = 0; i < 16; ++i) {
      unsigned phys = ((unsigned)i << 9) | (((unsigned)e0) ^ ((i & 7) << 2));
      *(u64*)(tileA + phys) = (u64)(unsigned)qa[i] | ((u64)(unsigned)qb[i] << 32);
    }
    __syncthreads();

    // ---- fragment reads (swizzled) + split-bf16 MFMA  [R6-proven] ----
    const unsigned swz = (unsigned)((l16 & 7) << 2);
    f32x4 a_hh = {0.f, 0.f, 0.f, 0.f};
    f32x4 a_lh = {0.f, 0.f, 0.f, 0.f};
    f32x4 a_hl = {0.f, 0.f, 0.f, 0.f};
#pragma unroll
    for (int ki = 0; ki < 16; ++ki) {
      int c0 = (ki << 5) + (quad << 3);
      const unsigned* lp0 = tileA + (l16 << 9) + ((unsigned)c0 ^ swz);
      const unsigned* lp1 = tileA + (l16 << 9) + ((unsigned)(c0 + 4) ^ swz);
      uint4v d0 = *(const uint4v*)lp0;
      uint4v d1 = *(const uint4v*)lp1;
      unsigned d[8] = {d0[0], d0[1], d0[2], d0[3], d1[0], d1[1], d1[2], d1[3]};
      uint4v vh, vl;
#pragma unroll
      for (int p = 0; p < 4; ++p) {
        vh[p] = __builtin_amdgcn_perm(d[2 * p + 1], d[2 * p], 0x07060302u);
        vl[p] = __builtin_amdgcn_perm(d[2 * p + 1], d[2 * p], 0x05040100u);
      }
      bf16x8 ah = __builtin_bit_cast(bf16x8, vh);
      bf16x8 al = __builtin_bit_cast(bf16x8, vl);
      a_hh = __builtin_amdgcn_mfma_f32_16x16x32_bf16(ah, Bhi[ki], a_hh, 0, 0, 0);
      a_lh = __builtin_amdgcn_mfma_f32_16x16x32_bf16(al, Bhi[ki], a_lh, 0, 0, 0);
      a_hl = __builtin_amdgcn_mfma_f32_16x16x32_bf16(ah, Blo[ki], a_hl, 0, 0, 0);
    }

    // C/D layout: row = quad*4 + r, col = l16  [R3-proven]
    const f32x4 xps = *(const f32x4*)(xp + t * BATCH + (gb << 4) + (quad << 2));
    const u64 tagw = ((u64)(unsigned)(t + 1)) << 32;
#pragma unroll
    for (int r = 0; r < 4; ++r) {
      float pre = a_hh[r] + a_lh[r] + a_hl[r] + xps[r] * win;
      float mm = fmaxf(fabsf(pre) + bm, 0.f);
      float hv = (pre > 0.f) ? mm : ((pre < 0.f) ? -mm : 0.f);
      int row = (quad << 2) + r;
      unsigned short hbv = f2bf(hv);
      unsigned short lbv = f2bf(hv - bf2f(hbv));
      u64 val = (u64)(((unsigned)hbv << 16) | (unsigned)lbv) | tagw;
      ast(nxt + (row << 9) + colg, val);  // single 8B store: data+tag atomic
    }
    __syncthreads();  // tileA reads done before next iteration overwrites
  }

  // ---- head: h_784 (tag 784) lives in buffer 0; poll-verify per element ----
  if (cg == 0) {
    int row = tid >> 4;  // 0..15
    int cls = tid & 15;
    if (cls < NCLS) {
      const u64* hf = g0 + (row << 9);
      float s = b_lin[cls];
      const float* wl = W_lin + cls * HDIM;
      for (int k = 0; k < HDIM; ++k) {
        u64 qv = ald(hf + k);
        int sp = 0;
        while ((unsigned)(qv >> 32) != (unsigned)TSTEPS) {
          qv = ald(hf + k);
          if (++sp > (1 << 20)) break;  // anti-hang valve
        }
        unsigned p = (unsigned)qv;
        s = fmaf(bf2f(p >> 16) + bf2f(p & 0xffffu), wl[k], s);
      }
      out[((gb << 4) + row) * NCLS + cls] = s;
    }
  }
}

extern "C" void kernel_launch(void* const* d_in, const int* in_sizes, int n_in,
                              void* d_out, int out_size, void* d_ws, size_t ws_size,
                              hipStream_t stream) {
  const float* inputs = (const float*)d_in[0];  // 256x784
  const int* perm = (const int*)d_in[1];        // 784 (int64 -> int32 by harness)
  const float* W_skew = (const float*)d_in[2];  // 512x512
  const float* W_in = (const float*)d_in[3];    // 512
  const float* b_mod = (const float*)d_in[4];   // 512
  const float* W_lin = (const float*)d_in[5];   // 10x512
  const float* b_lin = (const float*)d_in[6];   // 10
  float* out = (float*)d_out;

  // ws layout (with aliasing; stream order makes it safe):
  //   [0,1M)   X   (prologue)  -> h0 (1MB, memset AFTER gemms)
  //   [1M,2M)  P   = final Borth, persists through rnn_main
  //   [2M,3M)  Q   (prologue)  -> h1 (1MB, memset AFTER gemms)
  //   [3M,..)  xp  (784*256*4 = 0.77MB)
  char* ws = (char*)d_ws;
  float* X = (float*)ws;
  float* P = (float*)(ws + (1 << 20));
  float* Q = (float*)(ws + (2 << 20));
  float* xp = (float*)(ws + (3 << 20));
  u64* h0 = (u64*)ws;
  u64* h1 = (u64*)(ws + (2 << 20));

  gather_xp<<<TSTEPS, 256, 0, stream>>>(inputs, perm, xp);
  build_X<<<(HDIM * HDIM) / 256, 256, 0, stream>>>(W_skew, X);

  // expm(A) = (T6(A/32))^(2^5); final result lands in P
  axpyI<<<(HDIM * HDIM) / 256, 256, 0, stream>>>(P, X, 1.f / 6.f);
  float* a = P;
  float* b = Q;
  for (int k = 5; k >= 1; --k) {
    gemm512<<<dim3(8, 8), dim3(16, 16), 0, stream>>>(b, X, a, 1.f / (float)k, 1);
    float* tmp = a; a = b; b = tmp;
  }
  for (int i = 0; i < 5; ++i) {
    gemm512<<<dim3(8, 8), dim3(16, 16), 0, stream>>>(b, a, a, 1.f, 0);
    float* tmp = a; a = b; b = tmp;
  }
  // a == P here (5 Horner swaps + 5 squaring swaps return to P)

  // h buffers: zero AFTER the gemms (they alias X and Q).
  // h0 = zeros => (pk=0, tag=0) = valid h_0; h1 zeros never match tag>=1.
  hipMemsetAsync(h0, 0, (size_t)NGRP * 8192 * sizeof(u64), stream);
  hipMemsetAsync(h1, 0, (size_t)NGRP * 8192 * sizeof(u64), stream);

  rnn_main<<<NGRP * WGPG, 256, 0, stream>>>(xp, a, W_in, b_mod, W_lin, b_lin, h0, h1, out);
  (void)in_sizes; (void)n_in; (void)out_size; (void)ws_size;
}

// Round 10
// 2553.537 us; speedup vs baseline: 1.1357x; 1.1357x over previous
//
#include <hip/hip_runtime.h>

#define TSTEPS 784
#define BATCH  256
#define HDIM   512
#define NCLS   10
#define NGRP   16
#define WGPG   8

typedef __bf16 bf16x8 __attribute__((ext_vector_type(8)));
typedef float  f32x4  __attribute__((ext_vector_type(4)));
typedef unsigned uint4v __attribute__((ext_vector_type(4)));
typedef unsigned long long u64;
typedef unsigned short u16;

static __device__ __forceinline__ u16 f2bf(float f) {
  unsigned u = __builtin_bit_cast(unsigned, f);
  u += 0x7fffu + ((u >> 16) & 1u);
  return (u16)(u >> 16);
}
static __device__ __forceinline__ float bf2f(unsigned s) {
  unsigned u = s << 16;
  return __builtin_bit_cast(float, u);
}

// ---------------- xp[t][b] = inputs[b][perm[t]] ----------------
__global__ __launch_bounds__(256) void gather_xp(const float* __restrict__ in,
                                                 const int* __restrict__ perm,
                                                 float* __restrict__ xp) {
  int t = blockIdx.x;
  int b = threadIdx.x;
  int p = perm[t];
  p = (p < 0) ? 0 : (p >= TSTEPS ? TSTEPS - 1 : p);
  xp[t * BATCH + b] = in[b * TSTEPS + p];
}

// ---------------- X = (triu(W,1) - triu(W,1)^T) / 32 ----------------
__global__ __launch_bounds__(256) void build_X(const float* __restrict__ W,
                                               float* __restrict__ X) {
  int idx = blockIdx.x * 256 + threadIdx.x;
  int i = idx >> 9, j = idx & 511;
  float v = 0.f;
  if (j > i) v = W[i * HDIM + j];
  else if (i > j) v = -W[j * HDIM + i];
  X[idx] = v * 0.03125f;
}

// ---------------- P = coef*X + I ----------------
__global__ __launch_bounds__(256) void axpyI(float* __restrict__ P,
                                             const float* __restrict__ X, float coef) {
  int idx = blockIdx.x * 256 + threadIdx.x;
  int i = idx >> 9, j = idx & 511;
  P[idx] = coef * X[idx] + ((i == j) ? 1.f : 0.f);
}

// ---------------- C = alpha*A*B (+I), 512^3 fp32, 64x64 tile ----------------
// fp32 vector GEMM [R2-R8 proven]. The expm chain NEEDS fp32-class accuracy:
// split-bf16 here gave delta(Borth) ~1e-2 after 5 squarings -> absmax 12 (R9).
__global__ __launch_bounds__(256) void gemm512(float* __restrict__ C,
                                               const float* __restrict__ A,
                                               const float* __restrict__ B,
                                               float alpha, int addI) {
  __shared__ float As[16][68];
  __shared__ float Bs[16][68];
  const int tx = threadIdx.x, ty = threadIdx.y;
  const int tid = ty * 16 + tx;
  const int ib = blockIdx.y, jb = blockIdx.x;
  const int ra = tid >> 2, ca = (tid & 3) << 2;
  const int rb = tid >> 4, cb = (tid & 15) << 2;
  float acc[4][4] = {};
  for (int kt = 0; kt < HDIM / 16; ++kt) {
    f32x4 av = *(const f32x4*)(A + (ib * 64 + ra) * HDIM + kt * 16 + ca);
    f32x4 bv = *(const f32x4*)(B + (kt * 16 + rb) * HDIM + jb * 64 + cb);
    __syncthreads();
    As[ca + 0][ra] = av[0];
    As[ca + 1][ra] = av[1];
    As[ca + 2][ra] = av[2];
    As[ca + 3][ra] = av[3];
    *(f32x4*)&Bs[rb][cb] = bv;
    __syncthreads();
#pragma unroll
    for (int kk = 0; kk < 16; ++kk) {
      f32x4 a4 = *(const f32x4*)&As[kk][ty << 2];
      f32x4 b4 = *(const f32x4*)&Bs[kk][tx << 2];
#pragma unroll
      for (int u = 0; u < 4; ++u)
#pragma unroll
        for (int v = 0; v < 4; ++v) acc[u][v] = fmaf(a4[u], b4[v], acc[u][v]);
    }
  }
#pragma unroll
  for (int u = 0; u < 4; ++u)
#pragma unroll
    for (int v = 0; v < 4; ++v) {
      int r = ib * 64 + (ty << 2) + u, c = jb * 64 + (tx << 2) + v;
      float val = alpha * acc[u][v];
      if (addI && r == c) val += 1.f;
      C[r * HDIM + c] = val;
    }
}

// ---------------- persistent RNN scan: R6 structure + hi/lo planes ----------------
// 128 WGs x 256 thr. gb = wg&15, cg = wg>>4. h in global as TWO u16 planes
// (hi, lo) per buffer -> fragment ds_read_b128 yields bf16x8 DIRECTLY (no
// v_perm unpack). Flag barrier identical to R6 (drain-before-flag orders both
// plane stores; no tearing possible). Swizzle: phys_dword = (row<<8) |
// (dcol ^ ((row&7)<<2)) on 256-dword rows; XOR bits[4:2] preserves b64/b128.
__global__ __launch_bounds__(256, 1) void rnn_main(
    const float* __restrict__ xp, const float* __restrict__ Borth,
    const float* __restrict__ W_in, const float* __restrict__ b_mod,
    const float* __restrict__ W_lin, const float* __restrict__ b_lin,
    u16* __restrict__ h0hi, u16* __restrict__ h0lo, u16* __restrict__ h1hi,
    u16* __restrict__ h1lo, unsigned* __restrict__ flags, float* __restrict__ out) {
  __shared__ unsigned tileHi[4096], tileLo[4096];  // 16 KB + 16 KB

  const int wg = blockIdx.x;
  const int gb = wg & 15;
  const int cg = wg >> 4;
  const int tid = threadIdx.x;
  const int wave = tid >> 6;
  const int lane = tid & 63;
  const int quad = lane >> 4;
  const int l16 = lane & 15;
  const int colg = (cg << 6) + (wave << 4) + l16;

  // B fragments, register/AGPR-resident (round-hi split, R3-proven numerics)
  bf16x8 Bfh[16], Bfl[16];
#pragma unroll
  for (int ki = 0; ki < 16; ++ki) {
#pragma unroll
    for (int j = 0; j < 8; ++j) {
      int k = (ki << 5) + (quad << 3) + j;
      float v = Borth[k * HDIM + colg];
      u16 hb = f2bf(v);
      u16 lb = f2bf(v - bf2f(hb));
      Bfh[ki][j] = __builtin_bit_cast(__bf16, hb);
      Bfl[ki][j] = __builtin_bit_cast(__bf16, lb);
    }
  }
  const float win = W_in[colg];
  const float bm = b_mod[colg];

  u16* const g0h = h0hi + (gb << 13);  // 8192 u16 per group-plane
  u16* const g0l = h0lo + (gb << 13);
  u16* const g1h = h1hi + (gb << 13);
  u16* const g1l = h1lo + (gb << 13);
  unsigned* const myflag = flags + ((gb << 3) + cg) * 32;
  unsigned* const gflags = flags + (gb << 3) * 32;
  const unsigned swz = (unsigned)((l16 & 7) << 2);

  for (int t = 0; t < TSTEPS; ++t) {
    const u64* __restrict__ cH = (const u64*)((t & 1) ? g1h : g0h);
    const u64* __restrict__ cL = (const u64*)((t & 1) ? g1l : g0l);
    u16* __restrict__ nH = (t & 1) ? g0h : g1h;
    u16* __restrict__ nL = (t & 1) ? g0l : g1l;

    // ---- cooperative stage: 2048 u64 per plane; 16 loads in flight ----
    u64 qh[8], ql[8];
#pragma unroll
    for (int i = 0; i < 8; ++i) {
      qh[i] = __hip_atomic_load(cH + tid + (i << 8), __ATOMIC_RELAXED,
                                __HIP_MEMORY_SCOPE_AGENT);
      ql[i] = __hip_atomic_load(cL + tid + (i << 8), __ATOMIC_RELAXED,
                                __HIP_MEMORY_SCOPE_AGENT);
    }
#pragma unroll
    for (int i = 0; i < 8; ++i) {
      int f = tid + (i << 8);        // u64 index in 2048-u64 plane
      int r = f >> 7;                // row 0..15
      unsigned du = (unsigned)(f & 127) << 1;  // dword col (even)
      unsigned phys = ((unsigned)r << 8) | (du ^ ((r & 7) << 2));
      *(u64*)(tileHi + phys) = qh[i];
      *(u64*)(tileLo + phys) = ql[i];
    }
    __syncthreads();

    // ---- fragment reads (swizzled, NO perms) + split-bf16 MFMA ----
    f32x4 a_hh = {0.f, 0.f, 0.f, 0.f};
    f32x4 a_lh = {0.f, 0.f, 0.f, 0.f};
    f32x4 a_hl = {0.f, 0.f, 0.f, 0.f};
#pragma unroll
    for (int ki = 0; ki < 16; ++ki) {
      unsigned dcol0 = (unsigned)((ki << 4) + (quad << 2));
      unsigned off = ((unsigned)l16 << 8) + (dcol0 ^ swz);
      bf16x8 ah = __builtin_bit_cast(bf16x8, *(const uint4v*)(tileHi + off));
      bf16x8 al = __builtin_bit_cast(bf16x8, *(const uint4v*)(tileLo + off));
      a_hh = __builtin_amdgcn_mfma_f32_16x16x32_bf16(ah, Bfh[ki], a_hh, 0, 0, 0);
      a_lh = __builtin_amdgcn_mfma_f32_16x16x32_bf16(al, Bfh[ki], a_lh, 0, 0, 0);
      a_hl = __builtin_amdgcn_mfma_f32_16x16x32_bf16(ah, Bfl[ki], a_hl, 0, 0, 0);
    }

    // C/D layout: row = quad*4 + r, col = l16  [R3-proven]
    const f32x4 xps = *(const f32x4*)(xp + t * BATCH + (gb << 4) + (quad << 2));
#pragma unroll
    for (int r = 0; r < 4; ++r) {
      float pre = a_hh[r] + a_lh[r] + a_hl[r] + xps[r] * win;
      float mm = fmaxf(fabsf(pre) + bm, 0.f);
      float hv = (pre > 0.f) ? mm : ((pre < 0.f) ? -mm : 0.f);
      int idx = (((quad << 2) + r) << 9) + colg;
      u16 hbv = f2bf(hv);
      u16 lbv = f2bf(hv - bf2f(hbv));
      __hip_atomic_store(nH + idx, hbv, __ATOMIC_RELAXED, __HIP_MEMORY_SCOPE_AGENT);
      __hip_atomic_store(nL + idx, lbv, __ATOMIC_RELAXED, __HIP_MEMORY_SCOPE_AGENT);
    }

    // ---- flag barrier (8 WGs per group) [R6-proven] ----
    asm volatile("s_waitcnt vmcnt(0)" ::: "memory");  // both planes at coherence point
    __syncthreads();
    if (tid == 0)
      __hip_atomic_store(myflag, (unsigned)(t + 1), __ATOMIC_RELAXED,
                         __HIP_MEMORY_SCOPE_AGENT);
    const unsigned target = (unsigned)(t + 1);
    int spin = 0;
    for (;;) {
      unsigned fl = __hip_atomic_load(gflags + (lane & 7) * 32, __ATOMIC_RELAXED,
                                      __HIP_MEMORY_SCOPE_AGENT);
      if (__ballot(fl >= target) == ~0ull) break;
      __builtin_amdgcn_s_sleep(1);
      if (++spin > (1 << 22)) break;  // anti-hang valve
    }
  }

  // ---- head: final h in buffer 0 (t=783 odd -> writes g0) ----
  if (cg == 0) {
    int row = tid >> 4;
    int cls = tid & 15;
    if (cls < NCLS) {
      const u16* hh = g0h + (row << 9);
      const u16* hl = g0l + (row << 9);
      float s = b_lin[cls];
      const float* wl = W_lin + cls * HDIM;
      for (int k = 0; k < HDIM; ++k) {
        unsigned hu = __hip_atomic_load(hh + k, __ATOMIC_RELAXED, __HIP_MEMORY_SCOPE_AGENT);
        unsigned lu = __hip_atomic_load(hl + k, __ATOMIC_RELAXED, __HIP_MEMORY_SCOPE_AGENT);
        s = fmaf(bf2f(hu) + bf2f(lu), wl[k], s);
      }
      out[((gb << 4) + row) * NCLS + cls] = s;
    }
  }
}

extern "C" void kernel_launch(void* const* d_in, const int* in_sizes, int n_in,
                              void* d_out, int out_size, void* d_ws, size_t ws_size,
                              hipStream_t stream) {
  const float* inputs = (const float*)d_in[0];  // 256x784
  const int* perm = (const int*)d_in[1];        // 784 (int64 -> int32 by harness)
  const float* W_skew = (const float*)d_in[2];  // 512x512
  const float* W_in = (const float*)d_in[3];    // 512
  const float* b_mod = (const float*)d_in[4];   // 512
  const float* W_lin = (const float*)d_in[5];   // 10x512
  const float* b_lin = (const float*)d_in[6];   // 10
  float* out = (float*)d_out;

  char* ws = (char*)d_ws;
  unsigned* flags = (unsigned*)ws;            // 32 KB
  u16* h0hi = (u16*)(ws + 32768);             // 4 planes x 256 KB = 1 MB
  u16* h0lo = h0hi + BATCH * HDIM;
  u16* h1hi = h0lo + BATCH * HDIM;
  u16* h1lo = h1hi + BATCH * HDIM;
  float* xp = (float*)(h1lo + BATCH * HDIM);  // 0.77 MB
  float* X = xp + TSTEPS * BATCH;             // 1 MB
  float* P = X + HDIM * HDIM;                 // 1 MB
  float* Q = P + HDIM * HDIM;                 // 1 MB  (total ~4.9 MB)

  hipMemsetAsync(flags, 0, 32768, stream);
  hipMemsetAsync(h0hi, 0, (size_t)BATCH * HDIM * 2 * sizeof(u16), stream);  // h0 hi+lo

  gather_xp<<<TSTEPS, 256, 0, stream>>>(inputs, perm, xp);
  build_X<<<(HDIM * HDIM) / 256, 256, 0, stream>>>(W_skew, X);

  // expm(A) = (T6(A/32))^(2^5), Horner -- fp32 gemm512 [R2-R8 proven numerics]
  axpyI<<<(HDIM * HDIM) / 256, 256, 0, stream>>>(P, X, 1.f / 6.f);
  float* a = P;
  float* b = Q;
  for (int k = 5; k >= 1; --k) {
    gemm512<<<dim3(8, 8), dim3(16, 16), 0, stream>>>(b, X, a, 1.f / (float)k, 1);
    float* tmp = a; a = b; b = tmp;
  }
  for (int i = 0; i < 5; ++i) {
    gemm512<<<dim3(8, 8), dim3(16, 16), 0, stream>>>(b, a, a, 1.f, 0);
    float* tmp = a; a = b; b = tmp;
  }
  // a == P (10 swaps -> back to P)

  rnn_main<<<NGRP * WGPG, 256, 0, stream>>>(xp, a, W_in, b_mod, W_lin, b_lin,
                                            h0hi, h0lo, h1hi, h1lo, flags, out);
  (void)in_sizes; (void)n_in; (void)out_size; (void)ws_size;
}